// Round 1
// baseline (4157.434 us; speedup 1.0000x reference)
//
#include <hip/hip_runtime.h>

#define DEV_INLINE __device__ __forceinline__

DEV_INLINE float sigmoidf_(float x) { return 1.f / (1.f + __expf(-x)); }

// ---------------------------------------------------------------------------
// Generic tiled fp32 GEMM: C[M,N] = act(A[M,K] @ B[N,K]^T + bias) (+ res)
// ACT: 0 = none, 1 = DoubleSwish (x * sigmoid(x-1))
// ---------------------------------------------------------------------------
template<int ACT, bool RES>
__global__ __launch_bounds__(256) void gemm_kernel(
    const float* __restrict__ A, const float* __restrict__ B,
    const float* __restrict__ bias, const float* __restrict__ res,
    float* __restrict__ C, int M, int N, int K)
{
    __shared__ float As[64][17];
    __shared__ float Bs[64][17];
    const int t  = threadIdx.x;
    const int tx = t & 15, ty = t >> 4;
    const int m0 = blockIdx.y * 64, n0 = blockIdx.x * 64;

    float acc[4][4] = {};

    for (int k0 = 0; k0 < K; k0 += 16) {
#pragma unroll
        for (int i = 0; i < 4; i++) {
            int li = t + 256 * i;
            int m = li >> 4, kk = li & 15;
            int gm = m0 + m;
            As[m][kk] = (gm < M) ? A[(size_t)gm * K + k0 + kk] : 0.f;
        }
#pragma unroll
        for (int i = 0; i < 4; i++) {
            int li = t + 256 * i;
            int n = li >> 4, kk = li & 15;
            int gn = n0 + n;
            Bs[n][kk] = (gn < N) ? B[(size_t)gn * K + k0 + kk] : 0.f;
        }
        __syncthreads();
#pragma unroll
        for (int kk = 0; kk < 16; kk++) {
            float a[4], b[4];
#pragma unroll
            for (int i = 0; i < 4; i++) a[i] = As[ty * 4 + i][kk];
#pragma unroll
            for (int j = 0; j < 4; j++) b[j] = Bs[tx * 4 + j][kk];
#pragma unroll
            for (int i = 0; i < 4; i++)
#pragma unroll
                for (int j = 0; j < 4; j++)
                    acc[i][j] += a[i] * b[j];
        }
        __syncthreads();
    }

#pragma unroll
    for (int i = 0; i < 4; i++) {
        int gm = m0 + ty * 4 + i;
        if (gm >= M) continue;
#pragma unroll
        for (int j = 0; j < 4; j++) {
            int gn = n0 + tx * 4 + j;
            if (gn >= N) continue;
            float v = acc[i][j] + (bias ? bias[gn] : 0.f);
            if (ACT == 1) v = v * sigmoidf_(v - 1.f);
            if (RES) v += res[(size_t)gm * N + gn];
            C[(size_t)gm * N + gn] = v;
        }
    }
}

// ---------------------------------------------------------------------------
// Split qkv (L,N,768) into qu/qv/k/v in (N,H,L,d) layout; qu=q+pos_bias_u etc.
// ---------------------------------------------------------------------------
__global__ __launch_bounds__(256) void split_kernel(
    const float* __restrict__ qkv,
    const float* __restrict__ pbu, const float* __restrict__ pbv,
    float* __restrict__ qu, float* __restrict__ qv,
    float* __restrict__ kb, float* __restrict__ vb)
{
    int idx = blockIdx.x * 256 + threadIdx.x;   // ((n*8+h)*1024 + l)*32 + dd
    int dd = idx & 31;
    int l  = (idx >> 5) & 1023;
    int h  = (idx >> 15) & 7;
    int n  = idx >> 18;
    size_t base = ((size_t)l * 4 + n) * 768 + h * 32 + dd;
    float q = qkv[base];
    qu[idx] = q + pbu[h * 32 + dd];
    qv[idx] = q + pbv[h * 32 + dd];
    kb[idx] = qkv[base + 256];
    vb[idx] = qkv[base + 512];
}

// ---------------------------------------------------------------------------
// total[n,i,j,h] = (ac + bd)*scale + sum_g as[n,i,j,g]*proj_in[g,h]
// ac = (q+u)[n,h,i] . k[n,h,j] ; bd = (q+v)[n,h,i] . p[L-1-i+j, h]
// one block per (n,i); 256 threads; each thread handles 32 (j,h) pairs.
// ---------------------------------------------------------------------------
__global__ __launch_bounds__(256) void total_kernel(
    const float* __restrict__ qu, const float* __restrict__ qv,
    const float* __restrict__ kb, const float* __restrict__ pb,
    const float* __restrict__ as_, const float* __restrict__ proj_in,
    float* __restrict__ tot)
{
    const int L = 1024;
    int n = blockIdx.x >> 10;
    int i = blockIdx.x & 1023;
    int t = threadIdx.x;

    __shared__ __align__(16) float qus[8][32];
    __shared__ __align__(16) float qvs[8][32];
    __shared__ float pin[64];
    {
        int h = t >> 5, dd = t & 31;
        size_t qoff = ((size_t)(n * 8 + h) * 1024 + i) * 32 + dd;
        qus[h][dd] = qu[qoff];
        qvs[h][dd] = qv[qoff];
        if (t < 64) pin[t] = proj_in[t];
    }
    __syncthreads();

    const int h  = t & 7;
    const int j0 = t >> 3;
    const float4* qu4 = (const float4*)qus[h];
    const float4* qv4 = (const float4*)qvs[h];

    for (int it = 0; it < 32; it++) {
        int j = j0 + 32 * it;
        const float4* kr = (const float4*)(kb + ((size_t)(n * 8 + h) * 1024 + j) * 32);
        float ac = 0.f;
#pragma unroll
        for (int c = 0; c < 8; c++) {
            float4 kv = kr[c], qq = qu4[c];
            ac += kv.x * qq.x + kv.y * qq.y + kv.z * qq.z + kv.w * qq.w;
        }
        int m = (L - 1) - i + j;
        const float4* pr = (const float4*)(pb + ((size_t)m * 8 + h) * 32);
        float bd = 0.f;
#pragma unroll
        for (int c = 0; c < 8; c++) {
            float4 pv = pr[c], qq = qv4[c];
            bd += pv.x * qq.x + pv.y * qq.y + pv.z * qq.z + pv.w * qq.w;
        }
        const float* ar = as_ + (((size_t)n * L + i) * L + j) * 8;
        float si = 0.f;
#pragma unroll
        for (int g = 0; g < 8; g++) si += ar[g] * pin[g * 8 + h];
        tot[(((size_t)n * L + i) * L + j) * 8 + h] =
            (ac + bd) * 0.17677669529663687f + si;
    }
}

// ---------------------------------------------------------------------------
// scores_out[n,i,j,g] = sum_h tot[n,i,j,h]*proj_out[h,g] + as[n,i,j,g]
// ---------------------------------------------------------------------------
__global__ __launch_bounds__(256) void scores_out_kernel(
    const float* __restrict__ tot, const float* __restrict__ as_,
    const float* __restrict__ proj_out, float* __restrict__ out)
{
    __shared__ float po[64];
    if (threadIdx.x < 64) po[threadIdx.x] = proj_out[threadIdx.x];
    __syncthreads();
    size_t idx = (size_t)blockIdx.x * 256 + threadIdx.x;   // (n,i,j)
    const float4* t4 = (const float4*)(tot + idx * 8);
    float4 t0 = t4[0], t1 = t4[1];
    const float4* a4 = (const float4*)(as_ + idx * 8);
    float4 a0 = a4[0], a1 = a4[1];
    float th[8] = {t0.x, t0.y, t0.z, t0.w, t1.x, t1.y, t1.z, t1.w};
    float r[8];
#pragma unroll
    for (int g = 0; g < 8; g++) {
        float s = 0.f;
#pragma unroll
        for (int hh = 0; hh < 8; hh++) s += th[hh] * po[hh * 8 + g];
        r[g] = s;
    }
    float4 o0 = {r[0] + a0.x, r[1] + a0.y, r[2] + a0.z, r[3] + a0.w};
    float4 o1 = {r[4] + a1.x, r[5] + a1.y, r[6] + a1.z, r[7] + a1.w};
    float4* o4 = (float4*)(out + idx * 8);
    o4[0] = o0; o4[1] = o1;
}

// ---------------------------------------------------------------------------
// softmax over j for each (n,i,h); in-place on tot, layout (n,i,j,h)
// one block per (n,i): row = 1024*8 floats = 32KB in LDS
// ---------------------------------------------------------------------------
__global__ __launch_bounds__(256) void softmax_kernel(float* __restrict__ tot)
{
    int t = threadIdx.x;
    size_t base = (size_t)blockIdx.x * 8192;
    __shared__ __align__(16) float row[8192];
    __shared__ float red[4][2][4];
    __shared__ float gmax[8], gsum[8];
    float4* row4 = (float4*)row;
    float4* g4 = (float4*)(tot + base);

    const int hb = (t & 1) * 4;     // this thread's 4 h-values: hb..hb+3
    float lmax[4] = {-1e30f, -1e30f, -1e30f, -1e30f};
#pragma unroll
    for (int it = 0; it < 8; it++) {
        float4 v = g4[t + 256 * it];
        row4[t + 256 * it] = v;
        lmax[0] = fmaxf(lmax[0], v.x);
        lmax[1] = fmaxf(lmax[1], v.y);
        lmax[2] = fmaxf(lmax[2], v.z);
        lmax[3] = fmaxf(lmax[3], v.w);
    }
#pragma unroll
    for (int d = 2; d < 64; d <<= 1)
#pragma unroll
        for (int c = 0; c < 4; c++)
            lmax[c] = fmaxf(lmax[c], __shfl_xor(lmax[c], d));
    int wave = t >> 6, lane = t & 63;
    if (lane < 2)
#pragma unroll
        for (int c = 0; c < 4; c++) red[wave][lane][c] = lmax[c];
    __syncthreads();
    if (t < 8) {
        int p = t >> 2, c = t & 3;
        gmax[t] = fmaxf(fmaxf(red[0][p][c], red[1][p][c]),
                        fmaxf(red[2][p][c], red[3][p][c]));
    }
    __syncthreads();

    float mh[4];
#pragma unroll
    for (int c = 0; c < 4; c++) mh[c] = gmax[hb + c];
    float lsum[4] = {0.f, 0.f, 0.f, 0.f};
#pragma unroll
    for (int it = 0; it < 8; it++) {
        float4 v = row4[t + 256 * it];
        v.x = __expf(v.x - mh[0]);
        v.y = __expf(v.y - mh[1]);
        v.z = __expf(v.z - mh[2]);
        v.w = __expf(v.w - mh[3]);
        lsum[0] += v.x; lsum[1] += v.y; lsum[2] += v.z; lsum[3] += v.w;
        row4[t + 256 * it] = v;
    }
#pragma unroll
    for (int d = 2; d < 64; d <<= 1)
#pragma unroll
        for (int c = 0; c < 4; c++)
            lsum[c] += __shfl_xor(lsum[c], d);
    __syncthreads();   // red reuse
    if (lane < 2)
#pragma unroll
        for (int c = 0; c < 4; c++) red[wave][lane][c] = lsum[c];
    __syncthreads();
    if (t < 8) {
        int p = t >> 2, c = t & 3;
        gsum[t] = red[0][p][c] + red[1][p][c] + red[2][p][c] + red[3][p][c];
    }
    __syncthreads();

    float rs[4];
#pragma unroll
    for (int c = 0; c < 4; c++) rs[c] = 1.f / gsum[hb + c];
#pragma unroll
    for (int it = 0; it < 8; it++) {
        float4 v = row4[t + 256 * it];
        v.x *= rs[0]; v.y *= rs[1]; v.z *= rs[2]; v.w *= rs[3];
        g4[t + 256 * it] = v;
    }
}

// ---------------------------------------------------------------------------
// ctx_mat[(i*N+n)*256 + h*32+dd] = sum_j attn[n,i,j,h] * v[n,h,j,dd]
// one block per (n,i)
// ---------------------------------------------------------------------------
__global__ __launch_bounds__(256) void ctx_kernel(
    const float* __restrict__ attn, const float* __restrict__ vb,
    float* __restrict__ ctx_mat)
{
    int n = blockIdx.x >> 10, i = blockIdx.x & 1023;
    int t = threadIdx.x;
    __shared__ __align__(16) float row[8192];
    const float4* g4 = (const float4*)(attn + (size_t)blockIdx.x * 8192);
    float4* row4 = (float4*)row;
#pragma unroll
    for (int it = 0; it < 8; it++) row4[t + 256 * it] = g4[t + 256 * it];
    __syncthreads();
    int h = t >> 5, dd = t & 31;
    const float* vrow = vb + ((size_t)(n * 8 + h) * 1024) * 32 + dd;
    float acc = 0.f;
#pragma unroll 4
    for (int j = 0; j < 1024; j++)
        acc += row[j * 8 + h] * vrow[(size_t)j * 32];
    ctx_mat[((size_t)i * 4 + n) * 256 + h * 32 + dd] = acc;
}

// ---------------------------------------------------------------------------
// GLU: g[r,c] = h1[r,c] * sigmoid(h1[r,512+c]);  r over 4096, c over 512
// ---------------------------------------------------------------------------
__global__ __launch_bounds__(256) void glu_kernel(
    const float* __restrict__ h1, float* __restrict__ g)
{
    int idx = blockIdx.x * 256 + threadIdx.x;
    int r = idx >> 9, c = idx & 511;
    float a = h1[(size_t)r * 1024 + c];
    float b = h1[(size_t)r * 1024 + 512 + c];
    g[idx] = a * sigmoidf_(b);
}

// ---------------------------------------------------------------------------
// depthwise conv over l (K=31, pad 15) + bias + DoubleSwish
// layout (l*4+n)*512 + c
// ---------------------------------------------------------------------------
__global__ __launch_bounds__(256) void dwconv_kernel(
    const float* __restrict__ g, const float* __restrict__ w_dw,
    const float* __restrict__ b_dw, float* __restrict__ out)
{
    int idx = blockIdx.x * 256 + threadIdx.x;
    int c = idx & 511;
    int r = idx >> 9;
    int nn = r & 3, l = r >> 2;
    float acc = b_dw[c];
#pragma unroll
    for (int kk = 0; kk < 31; kk++) {
        int l2 = l + kk - 15;
        if (l2 >= 0 && l2 < 1024)
            acc += g[(((size_t)l2 * 4 + nn) << 9) + c] * w_dw[c * 31 + kk];
    }
    out[idx] = acc * sigmoidf_(acc - 1.f);
}

// ---------------------------------------------------------------------------
// BasicNorm: out = x * rsqrt(mean(x^2) + exp(eps)), rows of 512
// ---------------------------------------------------------------------------
__global__ __launch_bounds__(256) void norm_kernel(
    const float* __restrict__ x, const float* __restrict__ eps_p,
    float* __restrict__ out)
{
    int r = blockIdx.x, t = threadIdx.x;
    float a = x[(size_t)r * 512 + t];
    float b = x[(size_t)r * 512 + 256 + t];
    float ss = a * a + b * b;
#pragma unroll
    for (int d = 1; d < 64; d <<= 1) ss += __shfl_xor(ss, d);
    __shared__ float red[4];
    if ((t & 63) == 0) red[t >> 6] = ss;
    __syncthreads();
    float tot = red[0] + red[1] + red[2] + red[3];
    float scale = rsqrtf(tot * (1.f / 512.f) + __expf(eps_p[0]));
    out[(size_t)r * 512 + t] = a * scale;
    out[(size_t)r * 512 + 256 + t] = b * scale;
}

// ---------------------------------------------------------------------------
extern "C" void kernel_launch(void* const* d_in, const int* in_sizes, int n_in,
                              void* d_out, int out_size, void* d_ws, size_t ws_size,
                              hipStream_t stream)
{
    const float* src   = (const float*)d_in[0];
    const float* pos   = (const float*)d_in[1];
    const float* as_   = (const float*)d_in[2];
    const float* w_in  = (const float*)d_in[3];
    const float* b_in  = (const float*)d_in[4];
    const float* w_pos = (const float*)d_in[5];
    const float* pbu   = (const float*)d_in[6];
    const float* pbv   = (const float*)d_in[7];
    const float* prin  = (const float*)d_in[8];
    const float* prout = (const float*)d_in[9];
    const float* w_out = (const float*)d_in[10];
    const float* b_out = (const float*)d_in[11];
    const float* w_ff1m = (const float*)d_in[12];
    const float* b_ff1m = (const float*)d_in[13];
    const float* w_ff2m = (const float*)d_in[14];
    const float* b_ff2m = (const float*)d_in[15];
    const float* w_ff1 = (const float*)d_in[16];
    const float* b_ff1 = (const float*)d_in[17];
    const float* w_ff2 = (const float*)d_in[18];
    const float* b_ff2 = (const float*)d_in[19];
    const float* w_pw1 = (const float*)d_in[20];
    const float* b_pw1 = (const float*)d_in[21];
    const float* w_dw  = (const float*)d_in[22];
    const float* b_dw  = (const float*)d_in[23];
    const float* w_pw2 = (const float*)d_in[24];
    const float* b_pw2 = (const float*)d_in[25];
    const float* neps  = (const float*)d_in[26];

    float* out_x = (float*)d_out;                       // 4096*512
    float* out_s = (float*)d_out + 2097152;             // 4*1024*1024*8

    float* ws = (float*)d_ws;
    float* xbuf = ws;                   // 2,097,152
    float* hbuf = xbuf + 2097152;       // 8,388,608 (ffn hidden / pw1 / glu / dsw)
    float* qkvb = hbuf + 8388608;       // 3,145,728
    float* qu   = qkvb + 3145728;       // 1,048,576
    float* qv   = qu + 1048576;         // 1,048,576
    float* kbuf = qv + 1048576;         // 1,048,576
    float* vbuf = kbuf + 1048576;       // 1,048,576
    float* pbuf = vbuf + 1048576;       // 524,288 (2047*256 used)
    float* ctxm = pbuf + 524288;        // 1,048,576
    float* tot  = ctxm + 1048576;       // 33,554,432
    float* gbuf = hbuf + 4194304;       // within hbuf (after pw1's 4096*1024)
    float* dbuf = hbuf + 6291456;       // within hbuf

    const int M = 4096;
    dim3 blk(256);

    // --- macaron FFN ---
    gemm_kernel<1, false><<<dim3(2048/64, M/64), blk, 0, stream>>>(
        src, w_ff1m, b_ff1m, nullptr, hbuf, M, 2048, 512);
    gemm_kernel<0, true><<<dim3(512/64, M/64), blk, 0, stream>>>(
        hbuf, w_ff2m, b_ff2m, src, xbuf, M, 512, 2048);

    // --- attention ---
    gemm_kernel<0, false><<<dim3(768/64, M/64), blk, 0, stream>>>(
        xbuf, w_in, b_in, nullptr, qkvb, M, 768, 512);
    gemm_kernel<0, false><<<dim3(4, 32), blk, 0, stream>>>(
        pos, w_pos, nullptr, nullptr, pbuf, 2047, 256, 512);
    split_kernel<<<4096, blk, 0, stream>>>(qkvb, pbu, pbv, qu, qv, kbuf, vbuf);
    total_kernel<<<4096, blk, 0, stream>>>(qu, qv, kbuf, pbuf, as_, prin, tot);
    scores_out_kernel<<<16384, blk, 0, stream>>>(tot, as_, prout, out_s);
    softmax_kernel<<<4096, blk, 0, stream>>>(tot);
    ctx_kernel<<<4096, blk, 0, stream>>>(tot, vbuf, ctxm);
    gemm_kernel<0, true><<<dim3(512/64, M/64), blk, 0, stream>>>(
        ctxm, w_out, b_out, xbuf, xbuf, M, 512, 256);

    // --- conv module ---
    gemm_kernel<0, false><<<dim3(1024/64, M/64), blk, 0, stream>>>(
        xbuf, w_pw1, b_pw1, nullptr, hbuf, M, 1024, 512);
    glu_kernel<<<8192, blk, 0, stream>>>(hbuf, gbuf);
    dwconv_kernel<<<8192, blk, 0, stream>>>(gbuf, w_dw, b_dw, dbuf);
    gemm_kernel<0, true><<<dim3(512/64, M/64), blk, 0, stream>>>(
        dbuf, w_pw2, b_pw2, xbuf, xbuf, M, 512, 512);

    // --- final FFN + BasicNorm ---
    gemm_kernel<1, false><<<dim3(2048/64, M/64), blk, 0, stream>>>(
        xbuf, w_ff1, b_ff1, nullptr, hbuf, M, 2048, 512);
    gemm_kernel<0, true><<<dim3(512/64, M/64), blk, 0, stream>>>(
        hbuf, w_ff2, b_ff2, xbuf, xbuf, M, 512, 2048);
    norm_kernel<<<4096, blk, 0, stream>>>(xbuf, neps, out_x);
}

// Round 2
// 2202.815 us; speedup vs baseline: 1.8873x; 1.8873x over previous
//
#include <hip/hip_runtime.h>

#define DEV_INLINE __device__ __forceinline__

DEV_INLINE float sigmoidf_(float x) { return 1.f / (1.f + __expf(-x)); }
DEV_INLINE float dot4_(float4 a, float4 b) {
    return a.x * b.x + a.y * b.y + a.z * b.z + a.w * b.w;
}

// ---------------------------------------------------------------------------
// Generic tiled fp32 GEMM: C[M,N] = act(A[M,K] @ B[N,K]^T + bias) (+ res)
// ACT: 0 = none, 1 = DoubleSwish (x * sigmoid(x-1))
// ---------------------------------------------------------------------------
template<int ACT, bool RES>
__global__ __launch_bounds__(256) void gemm_kernel(
    const float* __restrict__ A, const float* __restrict__ B,
    const float* __restrict__ bias, const float* __restrict__ res,
    float* __restrict__ C, int M, int N, int K)
{
    __shared__ float As[64][17];
    __shared__ float Bs[64][17];
    const int t  = threadIdx.x;
    const int tx = t & 15, ty = t >> 4;
    const int m0 = blockIdx.y * 64, n0 = blockIdx.x * 64;

    float acc[4][4] = {};

    for (int k0 = 0; k0 < K; k0 += 16) {
#pragma unroll
        for (int i = 0; i < 4; i++) {
            int li = t + 256 * i;
            int m = li >> 4, kk = li & 15;
            int gm = m0 + m;
            As[m][kk] = (gm < M) ? A[(size_t)gm * K + k0 + kk] : 0.f;
        }
#pragma unroll
        for (int i = 0; i < 4; i++) {
            int li = t + 256 * i;
            int n = li >> 4, kk = li & 15;
            int gn = n0 + n;
            Bs[n][kk] = (gn < N) ? B[(size_t)gn * K + k0 + kk] : 0.f;
        }
        __syncthreads();
#pragma unroll
        for (int kk = 0; kk < 16; kk++) {
            float a[4], b[4];
#pragma unroll
            for (int i = 0; i < 4; i++) a[i] = As[ty * 4 + i][kk];
#pragma unroll
            for (int j = 0; j < 4; j++) b[j] = Bs[tx * 4 + j][kk];
#pragma unroll
            for (int i = 0; i < 4; i++)
#pragma unroll
                for (int j = 0; j < 4; j++)
                    acc[i][j] += a[i] * b[j];
        }
        __syncthreads();
    }

#pragma unroll
    for (int i = 0; i < 4; i++) {
        int gm = m0 + ty * 4 + i;
        if (gm >= M) continue;
#pragma unroll
        for (int j = 0; j < 4; j++) {
            int gn = n0 + tx * 4 + j;
            if (gn >= N) continue;
            float v = acc[i][j] + (bias ? bias[gn] : 0.f);
            if (ACT == 1) v = v * sigmoidf_(v - 1.f);
            if (RES) v += res[(size_t)gm * N + gn];
            C[(size_t)gm * N + gn] = v;
        }
    }
}

// ---------------------------------------------------------------------------
// Split qkv (L,N,768) into qu/qv/k/v in (N,H,L,d) layout; qu=q+pos_bias_u etc.
// ---------------------------------------------------------------------------
__global__ __launch_bounds__(256) void split_kernel(
    const float* __restrict__ qkv,
    const float* __restrict__ pbu, const float* __restrict__ pbv,
    float* __restrict__ qu, float* __restrict__ qv,
    float* __restrict__ kb, float* __restrict__ vb)
{
    int idx = blockIdx.x * 256 + threadIdx.x;   // ((n*8+h)*1024 + l)*32 + dd
    int dd = idx & 31;
    int l  = (idx >> 5) & 1023;
    int h  = (idx >> 15) & 7;
    int n  = idx >> 18;
    size_t base = ((size_t)l * 4 + n) * 768 + h * 32 + dd;
    float q = qkv[base];
    qu[idx] = q + pbu[h * 32 + dd];
    qv[idx] = q + pbv[h * 32 + dd];
    kb[idx] = qkv[base + 256];
    vb[idx] = qkv[base + 512];
}

// ---------------------------------------------------------------------------
// Repack p (m,h,d) -> p2 (h,m,d);  m in [0,2047)
// ---------------------------------------------------------------------------
__global__ __launch_bounds__(256) void repack_p_kernel(
    const float* __restrict__ pb, float* __restrict__ p2)
{
    int idx = blockIdx.x * 256 + threadIdx.x;
    if (idx >= 2047 * 256) return;
    int dd = idx & 31;
    int h  = (idx >> 5) & 7;
    int m  = idx >> 8;
    p2[((size_t)h * 2047 + m) * 32 + dd] = pb[idx];
}

// ---------------------------------------------------------------------------
// scores_kernel: tot[n,h,i,j] = (ac + bd) * scale
//   ac = qu[n,h,i,:] . k[n,h,j,:]
//   bd = qv[n,h,i,:] . p2[h, 1023-i+j, :]
// 64x64 tile per block, d=32 fully staged in LDS.
// ---------------------------------------------------------------------------
__global__ __launch_bounds__(256) void scores_kernel(
    const float* __restrict__ qu, const float* __restrict__ qv,
    const float* __restrict__ kb, const float* __restrict__ p2,
    float* __restrict__ tot)
{
    __shared__ float4 Qu4[8][64];
    __shared__ float4 Qv4[8][64];
    __shared__ float4 K4[8][64];
    __shared__ float4 P4[8][128];

    const int t = threadIdx.x;
    const int j0 = blockIdx.x * 64, i0 = blockIdx.y * 64;
    const int nh = blockIdx.z;       // n*8+h
    const int h = nh & 7;
    const int m_base = 960 - i0 + j0;    // = 1023 - (i0+63) + j0, always >= 0

    const float4* qug = (const float4*)(qu + ((size_t)nh * 1024 + i0) * 32);
    const float4* qvg = (const float4*)(qv + ((size_t)nh * 1024 + i0) * 32);
    const float4* kg  = (const float4*)(kb + ((size_t)nh * 1024 + j0) * 32);
    const float4* pg  = (const float4*)(p2 + ((size_t)h * 2047 + m_base) * 32);

#pragma unroll
    for (int c = 0; c < 2; c++) {
        int fi = t + 256 * c;
        int r = fi >> 3, dg = fi & 7;
        Qu4[dg][r] = qug[fi];
        Qv4[dg][r] = qvg[fi];
        K4[dg][r]  = kg[fi];
    }
#pragma unroll
    for (int c = 0; c < 4; c++) {
        int fi = t + 256 * c;
        if (fi < 127 * 8) {
            int r = fi >> 3, dg = fi & 7;
            P4[dg][r] = pg[fi];
        }
    }
    __syncthreads();

    const int tx = t & 15, ty = t >> 4;
    float acc[4][4] = {};

    // ---- ac: qu . k ----
#pragma unroll
    for (int dg = 0; dg < 8; dg++) {
        float4 a[4], b[4];
#pragma unroll
        for (int ii = 0; ii < 4; ii++) a[ii] = Qu4[dg][ty * 4 + ii];
#pragma unroll
        for (int jj = 0; jj < 4; jj++) b[jj] = K4[dg][tx * 4 + jj];
#pragma unroll
        for (int ii = 0; ii < 4; ii++)
#pragma unroll
            for (int jj = 0; jj < 4; jj++)
                acc[ii][jj] += dot4_(a[ii], b[jj]);
    }

    // ---- bd: qv . p[63 + jl - il] (local row) ----
    const int pb_ = 4 * (tx - ty) + 60;   // row for (ii=0,jj=0) minus 3... p_[s]=row pb_+s
#pragma unroll
    for (int dg = 0; dg < 8; dg++) {
        float4 qvr[4], pr[7];
#pragma unroll
        for (int ii = 0; ii < 4; ii++) qvr[ii] = Qv4[dg][ty * 4 + ii];
#pragma unroll
        for (int s = 0; s < 7; s++) pr[s] = P4[dg][pb_ + s];
#pragma unroll
        for (int ii = 0; ii < 4; ii++)
#pragma unroll
            for (int jj = 0; jj < 4; jj++)
                acc[ii][jj] += dot4_(qvr[ii], pr[jj - ii + 3]);
    }

    const float scale = 0.17677669529663687f;
    float* o = tot + ((size_t)nh * 1024 + i0) * 1024 + j0;
#pragma unroll
    for (int ii = 0; ii < 4; ii++) {
        float4 w = {acc[ii][0] * scale, acc[ii][1] * scale,
                    acc[ii][2] * scale, acc[ii][3] * scale};
        ((float4*)(o + (size_t)(ty * 4 + ii) * 1024))[tx] = w;
    }
}

// ---------------------------------------------------------------------------
// attn_finish_kernel: per (n,i):
//   th[h][j] = tot[n,h,i,j] + sum_g as[n,i,j,g]*pin[g,h]
//   out_s[n,i,j,g] = sum_h th[h][j]*po[h,g] + as[n,i,j,g]
//   tot[n,h,i,j] = softmax_j(th[h][j])
// ---------------------------------------------------------------------------
__global__ __launch_bounds__(256) void attn_finish_kernel(
    float* __restrict__ tot, const float* __restrict__ as_,
    const float* __restrict__ proj_in, const float* __restrict__ proj_out,
    float* __restrict__ out_s)
{
    __shared__ float row[8 * 1024];
    __shared__ float asb[1024 * 8];
    __shared__ float pin_s[64], po_s[64];
    __shared__ float rs_s[8];

    const int t = threadIdx.x;
    const int n = blockIdx.x >> 10;
    const int i = blockIdx.x & 1023;

    float4* row4 = (float4*)row;
    float4* asb4 = (float4*)asb;

    // load tot rows (8 h, each contiguous 1024) and as tile (contiguous 8192)
#pragma unroll
    for (int h = 0; h < 8; h++) {
        const float4* g4 = (const float4*)(tot + ((size_t)(n * 8 + h) * 1024 + i) * 1024);
        row4[h * 256 + t] = g4[t];
    }
    {
        const float4* a4 = (const float4*)(as_ + ((size_t)(n * 1024 + i) * 1024) * 8);
#pragma unroll
        for (int c = 0; c < 8; c++) asb4[t + 256 * c] = a4[t + 256 * c];
    }
    if (t < 64) { pin_s[t] = proj_in[t]; po_s[t] = proj_out[t]; }
    __syncthreads();

    // phase B: add proj_in.as to rows; emit scores_out
    float4* os4 = (float4*)(out_s + ((size_t)(n * 1024 + i) * 1024) * 8);
#pragma unroll
    for (int c = 0; c < 4; c++) {
        int j = t + 256 * c;
        float4 alo = asb4[j * 2], ahi = asb4[j * 2 + 1];
        float ag[8] = {alo.x, alo.y, alo.z, alo.w, ahi.x, ahi.y, ahi.z, ahi.w};
        float th[8];
#pragma unroll
        for (int h = 0; h < 8; h++) {
            float si = 0.f;
#pragma unroll
            for (int g = 0; g < 8; g++) si += ag[g] * pin_s[g * 8 + h];
            th[h] = row[h * 1024 + j] + si;
            row[h * 1024 + j] = th[h];
        }
        float so[8];
#pragma unroll
        for (int g = 0; g < 8; g++) {
            float s = ag[g];
#pragma unroll
            for (int h = 0; h < 8; h++) s += th[h] * po_s[h * 8 + g];
            so[g] = s;
        }
        float4 o0 = {so[0], so[1], so[2], so[3]};
        float4 o1 = {so[4], so[5], so[6], so[7]};
        os4[j * 2] = o0;
        os4[j * 2 + 1] = o1;
    }
    __syncthreads();

    // phase C: softmax per h-row; 32 threads per row, strided access
    {
        const int h = t >> 5, s = t & 31;
        float* r = row + h * 1024;
        float mx = -1e30f;
#pragma unroll 8
        for (int e = 0; e < 32; e++) mx = fmaxf(mx, r[e * 32 + s]);
#pragma unroll
        for (int d = 1; d < 32; d <<= 1) mx = fmaxf(mx, __shfl_xor(mx, d));
        float sm = 0.f;
#pragma unroll 8
        for (int e = 0; e < 32; e++) {
            float v = __expf(r[e * 32 + s] - mx);
            r[e * 32 + s] = v;
            sm += v;
        }
#pragma unroll
        for (int d = 1; d < 32; d <<= 1) sm += __shfl_xor(sm, d);
        if (s == 0) rs_s[h] = 1.f / sm;
    }
    __syncthreads();

    // phase D: normalize, write attn back to tot
#pragma unroll
    for (int h = 0; h < 8; h++) {
        float rs = rs_s[h];
        float4 v = row4[h * 256 + t];
        v.x *= rs; v.y *= rs; v.z *= rs; v.w *= rs;
        float4* g4 = (float4*)(tot + ((size_t)(n * 8 + h) * 1024 + i) * 1024);
        g4[t] = v;
    }
}

// ---------------------------------------------------------------------------
// ctx_kernel: per (n,h, i-tile of 64): ctx[i, n, h*32+d] = sum_j attn[i,j]*v[j,d]
// ---------------------------------------------------------------------------
__global__ __launch_bounds__(256) void ctx_kernel(
    const float* __restrict__ attn, const float* __restrict__ vb,
    float* __restrict__ ctx_mat)
{
    __shared__ float At[64][128];
    __shared__ float Vs[128][32];

    const int t = threadIdx.x;
    const int i0 = blockIdx.x * 64;
    const int nh = blockIdx.y;           // n*8+h
    const int n = nh >> 3, h = nh & 7;
    const int tx = t & 31, ty = t >> 5;  // tx = d, ty = i-group

    float acc[8] = {};
    const float* abase = attn + ((size_t)nh * 1024 + i0) * 1024;
    const float* vbase = vb + (size_t)nh * 1024 * 32;

    for (int jc = 0; jc < 8; jc++) {
#pragma unroll
        for (int c = 0; c < 8; c++) {
            int fi = t + 256 * c;             // 2048 float4
            int r = fi >> 5, c4 = fi & 31;
            ((float4*)At[r])[c4] =
                ((const float4*)(abase + (size_t)r * 1024 + jc * 128))[c4];
        }
#pragma unroll
        for (int c = 0; c < 4; c++) {
            int fi = t + 256 * c;             // 1024 float4
            int r = fi >> 3, dg = fi & 7;
            ((float4*)Vs[r])[dg] =
                ((const float4*)(vbase + (size_t)(jc * 128 + r) * 32))[dg];
        }
        __syncthreads();
#pragma unroll
        for (int jj = 0; jj < 32; jj++) {
            float v0 = Vs[jj * 4 + 0][tx];
            float v1 = Vs[jj * 4 + 1][tx];
            float v2 = Vs[jj * 4 + 2][tx];
            float v3 = Vs[jj * 4 + 3][tx];
#pragma unroll
            for (int ii = 0; ii < 8; ii++) {
                float4 av = ((float4*)At[ty * 8 + ii])[jj];
                acc[ii] += av.x * v0 + av.y * v1 + av.z * v2 + av.w * v3;
            }
        }
        __syncthreads();
    }

#pragma unroll
    for (int ii = 0; ii < 8; ii++) {
        int i = i0 + ty * 8 + ii;
        ctx_mat[((size_t)i * 4 + n) * 256 + h * 32 + tx] = acc[ii];
    }
}

// ---------------------------------------------------------------------------
// GLU: g[r,c] = h1[r,c] * sigmoid(h1[r,512+c]);  r over 4096, c over 512
// ---------------------------------------------------------------------------
__global__ __launch_bounds__(256) void glu_kernel(
    const float* __restrict__ h1, float* __restrict__ g)
{
    int idx = blockIdx.x * 256 + threadIdx.x;
    int r = idx >> 9, c = idx & 511;
    float a = h1[(size_t)r * 1024 + c];
    float b = h1[(size_t)r * 1024 + 512 + c];
    g[idx] = a * sigmoidf_(b);
}

// ---------------------------------------------------------------------------
// depthwise conv over l (K=31, pad 15) + bias + DoubleSwish
// layout (l*4+n)*512 + c
// ---------------------------------------------------------------------------
__global__ __launch_bounds__(256) void dwconv_kernel(
    const float* __restrict__ g, const float* __restrict__ w_dw,
    const float* __restrict__ b_dw, float* __restrict__ out)
{
    int idx = blockIdx.x * 256 + threadIdx.x;
    int c = idx & 511;
    int r = idx >> 9;
    int nn = r & 3, l = r >> 2;
    float acc = b_dw[c];
#pragma unroll
    for (int kk = 0; kk < 31; kk++) {
        int l2 = l + kk - 15;
        if (l2 >= 0 && l2 < 1024)
            acc += g[(((size_t)l2 * 4 + nn) << 9) + c] * w_dw[c * 31 + kk];
    }
    out[idx] = acc * sigmoidf_(acc - 1.f);
}

// ---------------------------------------------------------------------------
// BasicNorm: out = x * rsqrt(mean(x^2) + exp(eps)), rows of 512
// ---------------------------------------------------------------------------
__global__ __launch_bounds__(256) void norm_kernel(
    const float* __restrict__ x, const float* __restrict__ eps_p,
    float* __restrict__ out)
{
    int r = blockIdx.x, t = threadIdx.x;
    float a = x[(size_t)r * 512 + t];
    float b = x[(size_t)r * 512 + 256 + t];
    float ss = a * a + b * b;
#pragma unroll
    for (int d = 1; d < 64; d <<= 1) ss += __shfl_xor(ss, d);
    __shared__ float red[4];
    if ((t & 63) == 0) red[t >> 6] = ss;
    __syncthreads();
    float tot = red[0] + red[1] + red[2] + red[3];
    float scale = rsqrtf(tot * (1.f / 512.f) + __expf(eps_p[0]));
    out[(size_t)r * 512 + t] = a * scale;
    out[(size_t)r * 512 + 256 + t] = b * scale;
}

// ---------------------------------------------------------------------------
extern "C" void kernel_launch(void* const* d_in, const int* in_sizes, int n_in,
                              void* d_out, int out_size, void* d_ws, size_t ws_size,
                              hipStream_t stream)
{
    const float* src   = (const float*)d_in[0];
    const float* pos   = (const float*)d_in[1];
    const float* as_   = (const float*)d_in[2];
    const float* w_in  = (const float*)d_in[3];
    const float* b_in  = (const float*)d_in[4];
    const float* w_pos = (const float*)d_in[5];
    const float* pbu   = (const float*)d_in[6];
    const float* pbv   = (const float*)d_in[7];
    const float* prin  = (const float*)d_in[8];
    const float* prout = (const float*)d_in[9];
    const float* w_out = (const float*)d_in[10];
    const float* b_out = (const float*)d_in[11];
    const float* w_ff1m = (const float*)d_in[12];
    const float* b_ff1m = (const float*)d_in[13];
    const float* w_ff2m = (const float*)d_in[14];
    const float* b_ff2m = (const float*)d_in[15];
    const float* w_ff1 = (const float*)d_in[16];
    const float* b_ff1 = (const float*)d_in[17];
    const float* w_ff2 = (const float*)d_in[18];
    const float* b_ff2 = (const float*)d_in[19];
    const float* w_pw1 = (const float*)d_in[20];
    const float* b_pw1 = (const float*)d_in[21];
    const float* w_dw  = (const float*)d_in[22];
    const float* b_dw  = (const float*)d_in[23];
    const float* w_pw2 = (const float*)d_in[24];
    const float* b_pw2 = (const float*)d_in[25];
    const float* neps  = (const float*)d_in[26];

    float* out_x = (float*)d_out;                       // 4096*512
    float* out_s = (float*)d_out + 2097152;             // 4*1024*1024*8

    float* ws = (float*)d_ws;
    float* xbuf = ws;                   // 2,097,152
    float* hbuf = xbuf + 2097152;       // 8,388,608
    float* qkvb = hbuf + 8388608;       // 3,145,728
    float* qu   = qkvb + 3145728;       // 1,048,576
    float* qv   = qu + 1048576;         // 1,048,576
    float* kbuf = qv + 1048576;         // 1,048,576
    float* vbuf = kbuf + 1048576;       // 1,048,576
    float* pbuf = vbuf + 1048576;       // 524,288 (2047*256 used)
    float* ctxm = pbuf + 524288;        // 1,048,576
    float* tot  = ctxm + 1048576;       // 33,554,432  (layout n,h,i,j)
    float* p2   = qkvb;                 // reuse qkv buffer after split (524,032)
    float* gbuf = hbuf + 4194304;
    float* dbuf = hbuf + 6291456;

    const int M = 4096;
    dim3 blk(256);

    // --- macaron FFN ---
    gemm_kernel<1, false><<<dim3(2048/64, M/64), blk, 0, stream>>>(
        src, w_ff1m, b_ff1m, nullptr, hbuf, M, 2048, 512);
    gemm_kernel<0, true><<<dim3(512/64, M/64), blk, 0, stream>>>(
        hbuf, w_ff2m, b_ff2m, src, xbuf, M, 512, 2048);

    // --- attention ---
    gemm_kernel<0, false><<<dim3(768/64, M/64), blk, 0, stream>>>(
        xbuf, w_in, b_in, nullptr, qkvb, M, 768, 512);
    gemm_kernel<0, false><<<dim3(4, 32), blk, 0, stream>>>(
        pos, w_pos, nullptr, nullptr, pbuf, 2047, 256, 512);
    split_kernel<<<4096, blk, 0, stream>>>(qkvb, pbu, pbv, qu, qv, kbuf, vbuf);
    repack_p_kernel<<<2047, blk, 0, stream>>>(pbuf, p2);
    scores_kernel<<<dim3(16, 16, 32), blk, 0, stream>>>(qu, qv, kbuf, p2, tot);
    attn_finish_kernel<<<4096, blk, 0, stream>>>(tot, as_, prin, prout, out_s);
    ctx_kernel<<<dim3(16, 32), blk, 0, stream>>>(tot, vbuf, ctxm);
    gemm_kernel<0, true><<<dim3(512/64, M/64), blk, 0, stream>>>(
        ctxm, w_out, b_out, xbuf, xbuf, M, 512, 256);

    // --- conv module ---
    gemm_kernel<0, false><<<dim3(1024/64, M/64), blk, 0, stream>>>(
        xbuf, w_pw1, b_pw1, nullptr, hbuf, M, 1024, 512);
    glu_kernel<<<8192, blk, 0, stream>>>(hbuf, gbuf);
    dwconv_kernel<<<8192, blk, 0, stream>>>(gbuf, w_dw, b_dw, dbuf);
    gemm_kernel<0, true><<<dim3(512/64, M/64), blk, 0, stream>>>(
        dbuf, w_pw2, b_pw2, xbuf, xbuf, M, 512, 512);

    // --- final FFN + BasicNorm ---
    gemm_kernel<1, false><<<dim3(2048/64, M/64), blk, 0, stream>>>(
        xbuf, w_ff1, b_ff1, nullptr, hbuf, M, 2048, 512);
    gemm_kernel<0, true><<<dim3(512/64, M/64), blk, 0, stream>>>(
        hbuf, w_ff2, b_ff2, xbuf, xbuf, M, 512, 2048);
    norm_kernel<<<4096, blk, 0, stream>>>(xbuf, neps, out_x);
}

// Round 3
// 860.398 us; speedup vs baseline: 4.8320x; 2.5602x over previous
//
#include <hip/hip_runtime.h>

#define DEV_INLINE __device__ __forceinline__

typedef short bf16x8 __attribute__((ext_vector_type(8)));
typedef float f32x4 __attribute__((ext_vector_type(4)));

DEV_INLINE float sigmoidf_(float x) { return 1.f / (1.f + __expf(-x)); }
DEV_INLINE float dot4_(float4 a, float4 b) {
    return a.x * b.x + a.y * b.y + a.z * b.z + a.w * b.w;
}
DEV_INLINE unsigned short f2bf(float x) {
    unsigned int u = __float_as_uint(x);
    unsigned int r = (u + 0x7FFFu + ((u >> 16) & 1u)) >> 16;
    return (unsigned short)r;
}

// ---------------------------------------------------------------------------
// cast fp32 -> bf16 (RNE), vectorized x4
// ---------------------------------------------------------------------------
__global__ __launch_bounds__(256) void cast_bf16_kernel(
    const float4* __restrict__ in, ushort4* __restrict__ out)
{
    int i = blockIdx.x * 256 + threadIdx.x;
    float4 v = in[i];
    ushort4 o = {f2bf(v.x), f2bf(v.y), f2bf(v.z), f2bf(v.w)};
    out[i] = o;
}

// ---------------------------------------------------------------------------
// bf16 MFMA GEMM (m97 structure): C[M,N] = act(A[M,K] @ B[N,K]^T + bias)(+res)
// 128x128 tile, BK=32, 4 waves, 4x4 16x16x32 fragments per wave.
// A,B bf16 row-major [rows][K]. Optional fp32 + bf16 dual output.
// ---------------------------------------------------------------------------
template<int ACT, int RES, int WF32, int WBF>
__global__ __launch_bounds__(256) void mfma_gemm(
    const unsigned short* __restrict__ A, const unsigned short* __restrict__ B,
    const float* __restrict__ bias, const float* __restrict__ res,
    float* __restrict__ C, unsigned short* __restrict__ Cb, int M, int N, int K)
{
    __shared__ __align__(16) unsigned short As[128 * 32];
    __shared__ __align__(16) unsigned short Bs[128 * 32];

    const int t = threadIdx.x;
    const int lane = t & 63, wave = t >> 6;
    const int wr = wave >> 1, wc = wave & 1;
    const int lr = lane & 15, lk = lane >> 4;
    const int m0 = blockIdx.y * 128, n0 = blockIdx.x * 128;

    f32x4 acc[4][4] = {};

    for (int k0 = 0; k0 < K; k0 += 32) {
#pragma unroll
        for (int c = 0; c < 2; c++) {
            int bo = t * 16 + c * 4096;       // byte offset into 8KB tile
            int row = bo >> 6;                // 64 B per row (32 bf16)
            int col = (bo & 63) >> 1;
            __builtin_amdgcn_global_load_lds(
                (const __attribute__((address_space(1))) void*)(A + (size_t)(m0 + row) * K + k0 + col),
                (__attribute__((address_space(3))) void*)(As + (bo >> 1)), 16, 0, 0);
            __builtin_amdgcn_global_load_lds(
                (const __attribute__((address_space(1))) void*)(B + (size_t)(n0 + row) * K + k0 + col),
                (__attribute__((address_space(3))) void*)(Bs + (bo >> 1)), 16, 0, 0);
        }
        __syncthreads();

        bf16x8 af[4], bfr[4];
#pragma unroll
        for (int mi = 0; mi < 4; mi++)
            af[mi] = *(const bf16x8*)(As + (wr * 64 + mi * 16 + lr) * 32 + lk * 8);
#pragma unroll
        for (int nj = 0; nj < 4; nj++)
            bfr[nj] = *(const bf16x8*)(Bs + (wc * 64 + nj * 16 + lr) * 32 + lk * 8);
#pragma unroll
        for (int mi = 0; mi < 4; mi++)
#pragma unroll
            for (int nj = 0; nj < 4; nj++)
                acc[mi][nj] = __builtin_amdgcn_mfma_f32_16x16x32_bf16(
                    af[mi], bfr[nj], acc[mi][nj], 0, 0, 0);
        __syncthreads();
    }

#pragma unroll
    for (int nj = 0; nj < 4; nj++) {
        int col = n0 + wc * 64 + nj * 16 + lr;
        float bv = bias[col];
#pragma unroll
        for (int mi = 0; mi < 4; mi++) {
            int row = m0 + wr * 64 + mi * 16 + lk * 4;
#pragma unroll
            for (int j = 0; j < 4; j++) {
                float v = acc[mi][nj][j] + bv;
                if (ACT) v = v * sigmoidf_(v - 1.f);
                size_t off = (size_t)(row + j) * N + col;
                if (RES) v += res[off];
                if (WF32) C[off] = v;
                if (WBF) Cb[off] = f2bf(v);
            }
        }
    }
}

// ---------------------------------------------------------------------------
// fp32 tiled GEMM (kept for pos_emb projection, M=2047)
// ---------------------------------------------------------------------------
__global__ __launch_bounds__(256) void gemm_kernel(
    const float* __restrict__ A, const float* __restrict__ B,
    const float* __restrict__ bias, float* __restrict__ C, int M, int N, int K)
{
    __shared__ float As[64][17];
    __shared__ float Bs[64][17];
    const int t  = threadIdx.x;
    const int tx = t & 15, ty = t >> 4;
    const int m0 = blockIdx.y * 64, n0 = blockIdx.x * 64;

    float acc[4][4] = {};

    for (int k0 = 0; k0 < K; k0 += 16) {
#pragma unroll
        for (int i = 0; i < 4; i++) {
            int li = t + 256 * i;
            int m = li >> 4, kk = li & 15;
            int gm = m0 + m;
            As[m][kk] = (gm < M) ? A[(size_t)gm * K + k0 + kk] : 0.f;
        }
#pragma unroll
        for (int i = 0; i < 4; i++) {
            int li = t + 256 * i;
            int n = li >> 4, kk = li & 15;
            int gn = n0 + n;
            Bs[n][kk] = (gn < N) ? B[(size_t)gn * K + k0 + kk] : 0.f;
        }
        __syncthreads();
#pragma unroll
        for (int kk = 0; kk < 16; kk++) {
            float a[4], b[4];
#pragma unroll
            for (int i = 0; i < 4; i++) a[i] = As[ty * 4 + i][kk];
#pragma unroll
            for (int j = 0; j < 4; j++) b[j] = Bs[tx * 4 + j][kk];
#pragma unroll
            for (int i = 0; i < 4; i++)
#pragma unroll
                for (int j = 0; j < 4; j++)
                    acc[i][j] += a[i] * b[j];
        }
        __syncthreads();
    }

#pragma unroll
    for (int i = 0; i < 4; i++) {
        int gm = m0 + ty * 4 + i;
        if (gm >= M) continue;
#pragma unroll
        for (int j = 0; j < 4; j++) {
            int gn = n0 + tx * 4 + j;
            if (gn >= N) continue;
            float v = acc[i][j] + (bias ? bias[gn] : 0.f);
            C[(size_t)gm * N + gn] = v;
        }
    }
}

// ---------------------------------------------------------------------------
// Split qkv (L,N,768) into qu/qv/k/v in (N,H,L,d) layout; qu=q+pos_bias_u etc.
// ---------------------------------------------------------------------------
__global__ __launch_bounds__(256) void split_kernel(
    const float* __restrict__ qkv,
    const float* __restrict__ pbu, const float* __restrict__ pbv,
    float* __restrict__ qu, float* __restrict__ qv,
    float* __restrict__ kb, float* __restrict__ vb)
{
    int idx = blockIdx.x * 256 + threadIdx.x;   // ((n*8+h)*1024 + l)*32 + dd
    int dd = idx & 31;
    int l  = (idx >> 5) & 1023;
    int h  = (idx >> 15) & 7;
    int n  = idx >> 18;
    size_t base = ((size_t)l * 4 + n) * 768 + h * 32 + dd;
    float q = qkv[base];
    qu[idx] = q + pbu[h * 32 + dd];
    qv[idx] = q + pbv[h * 32 + dd];
    kb[idx] = qkv[base + 256];
    vb[idx] = qkv[base + 512];
}

// ---------------------------------------------------------------------------
// Repack p (m,h,d) -> p2 (h,m,d);  m in [0,2047)
// ---------------------------------------------------------------------------
__global__ __launch_bounds__(256) void repack_p_kernel(
    const float* __restrict__ pb, float* __restrict__ p2)
{
    int idx = blockIdx.x * 256 + threadIdx.x;
    if (idx >= 2047 * 256) return;
    int dd = idx & 31;
    int h  = (idx >> 5) & 7;
    int m  = idx >> 8;
    p2[((size_t)h * 2047 + m) * 32 + dd] = pb[idx];
}

// ---------------------------------------------------------------------------
// scores_kernel: tot[n,h,i,j] = (ac + bd) * scale
// ---------------------------------------------------------------------------
__global__ __launch_bounds__(256) void scores_kernel(
    const float* __restrict__ qu, const float* __restrict__ qv,
    const float* __restrict__ kb, const float* __restrict__ p2,
    float* __restrict__ tot)
{
    __shared__ float4 Qu4[8][64];
    __shared__ float4 Qv4[8][64];
    __shared__ float4 K4[8][64];
    __shared__ float4 P4[8][128];

    const int t = threadIdx.x;
    const int j0 = blockIdx.x * 64, i0 = blockIdx.y * 64;
    const int nh = blockIdx.z;       // n*8+h
    const int h = nh & 7;
    const int m_base = 960 - i0 + j0;

    const float4* qug = (const float4*)(qu + ((size_t)nh * 1024 + i0) * 32);
    const float4* qvg = (const float4*)(qv + ((size_t)nh * 1024 + i0) * 32);
    const float4* kg  = (const float4*)(kb + ((size_t)nh * 1024 + j0) * 32);
    const float4* pg  = (const float4*)(p2 + ((size_t)h * 2047 + m_base) * 32);

#pragma unroll
    for (int c = 0; c < 2; c++) {
        int fi = t + 256 * c;
        int r = fi >> 3, dg = fi & 7;
        Qu4[dg][r] = qug[fi];
        Qv4[dg][r] = qvg[fi];
        K4[dg][r]  = kg[fi];
    }
#pragma unroll
    for (int c = 0; c < 4; c++) {
        int fi = t + 256 * c;
        if (fi < 127 * 8) {
            int r = fi >> 3, dg = fi & 7;
            P4[dg][r] = pg[fi];
        }
    }
    __syncthreads();

    const int tx = t & 15, ty = t >> 4;
    float acc[4][4] = {};

#pragma unroll
    for (int dg = 0; dg < 8; dg++) {
        float4 a[4], b[4];
#pragma unroll
        for (int ii = 0; ii < 4; ii++) a[ii] = Qu4[dg][ty * 4 + ii];
#pragma unroll
        for (int jj = 0; jj < 4; jj++) b[jj] = K4[dg][tx * 4 + jj];
#pragma unroll
        for (int ii = 0; ii < 4; ii++)
#pragma unroll
            for (int jj = 0; jj < 4; jj++)
                acc[ii][jj] += dot4_(a[ii], b[jj]);
    }

    const int pb_ = 4 * (tx - ty) + 60;
#pragma unroll
    for (int dg = 0; dg < 8; dg++) {
        float4 qvr[4], pr[7];
#pragma unroll
        for (int ii = 0; ii < 4; ii++) qvr[ii] = Qv4[dg][ty * 4 + ii];
#pragma unroll
        for (int s = 0; s < 7; s++) pr[s] = P4[dg][pb_ + s];
#pragma unroll
        for (int ii = 0; ii < 4; ii++)
#pragma unroll
            for (int jj = 0; jj < 4; jj++)
                acc[ii][jj] += dot4_(qvr[ii], pr[jj - ii + 3]);
    }

    const float scale = 0.17677669529663687f;
    float* o = tot + ((size_t)nh * 1024 + i0) * 1024 + j0;
#pragma unroll
    for (int ii = 0; ii < 4; ii++) {
        float4 w = {acc[ii][0] * scale, acc[ii][1] * scale,
                    acc[ii][2] * scale, acc[ii][3] * scale};
        ((float4*)(o + (size_t)(ty * 4 + ii) * 1024))[tx] = w;
    }
}

// ---------------------------------------------------------------------------
// attn_finish_kernel: +proj_in.as, scores_out, softmax (in-place on tot)
// ---------------------------------------------------------------------------
__global__ __launch_bounds__(256) void attn_finish_kernel(
    float* __restrict__ tot, const float* __restrict__ as_,
    const float* __restrict__ proj_in, const float* __restrict__ proj_out,
    float* __restrict__ out_s)
{
    __shared__ float row[8 * 1024];
    __shared__ float asb[1024 * 8];
    __shared__ float pin_s[64], po_s[64];
    __shared__ float rs_s[8];

    const int t = threadIdx.x;
    const int n = blockIdx.x >> 10;
    const int i = blockIdx.x & 1023;

    float4* row4 = (float4*)row;
    float4* asb4 = (float4*)asb;

#pragma unroll
    for (int h = 0; h < 8; h++) {
        const float4* g4 = (const float4*)(tot + ((size_t)(n * 8 + h) * 1024 + i) * 1024);
        row4[h * 256 + t] = g4[t];
    }
    {
        const float4* a4 = (const float4*)(as_ + ((size_t)(n * 1024 + i) * 1024) * 8);
#pragma unroll
        for (int c = 0; c < 8; c++) asb4[t + 256 * c] = a4[t + 256 * c];
    }
    if (t < 64) { pin_s[t] = proj_in[t]; po_s[t] = proj_out[t]; }
    __syncthreads();

    float4* os4 = (float4*)(out_s + ((size_t)(n * 1024 + i) * 1024) * 8);
#pragma unroll
    for (int c = 0; c < 4; c++) {
        int j = t + 256 * c;
        float4 alo = asb4[j * 2], ahi = asb4[j * 2 + 1];
        float ag[8] = {alo.x, alo.y, alo.z, alo.w, ahi.x, ahi.y, ahi.z, ahi.w};
        float th[8];
#pragma unroll
        for (int h = 0; h < 8; h++) {
            float si = 0.f;
#pragma unroll
            for (int g = 0; g < 8; g++) si += ag[g] * pin_s[g * 8 + h];
            th[h] = row[h * 1024 + j] + si;
            row[h * 1024 + j] = th[h];
        }
        float so[8];
#pragma unroll
        for (int g = 0; g < 8; g++) {
            float s = ag[g];
#pragma unroll
            for (int h = 0; h < 8; h++) s += th[h] * po_s[h * 8 + g];
            so[g] = s;
        }
        float4 o0 = {so[0], so[1], so[2], so[3]};
        float4 o1 = {so[4], so[5], so[6], so[7]};
        os4[j * 2] = o0;
        os4[j * 2 + 1] = o1;
    }
    __syncthreads();

    {
        const int h = t >> 5, s = t & 31;
        float* r = row + h * 1024;
        float mx = -1e30f;
#pragma unroll 8
        for (int e = 0; e < 32; e++) mx = fmaxf(mx, r[e * 32 + s]);
#pragma unroll
        for (int d = 1; d < 32; d <<= 1) mx = fmaxf(mx, __shfl_xor(mx, d));
        float sm = 0.f;
#pragma unroll 8
        for (int e = 0; e < 32; e++) {
            float v = __expf(r[e * 32 + s] - mx);
            r[e * 32 + s] = v;
            sm += v;
        }
#pragma unroll
        for (int d = 1; d < 32; d <<= 1) sm += __shfl_xor(sm, d);
        if (s == 0) rs_s[h] = 1.f / sm;
    }
    __syncthreads();

#pragma unroll
    for (int h = 0; h < 8; h++) {
        float rs = rs_s[h];
        float4 v = row4[h * 256 + t];
        v.x *= rs; v.y *= rs; v.z *= rs; v.w *= rs;
        float4* g4 = (float4*)(tot + ((size_t)(n * 8 + h) * 1024 + i) * 1024);
        g4[t] = v;
    }
}

// ---------------------------------------------------------------------------
// ctx_kernel: ctx[i, n, h*32+d] = sum_j attn[i,j]*v[j,d]  (bf16 output)
// ---------------------------------------------------------------------------
__global__ __launch_bounds__(256) void ctx_kernel(
    const float* __restrict__ attn, const float* __restrict__ vb,
    unsigned short* __restrict__ ctx_b)
{
    __shared__ float At[64][128];
    __shared__ float Vs[128][32];

    const int t = threadIdx.x;
    const int i0 = blockIdx.x * 64;
    const int nh = blockIdx.y;           // n*8+h
    const int n = nh >> 3, h = nh & 7;
    const int tx = t & 31, ty = t >> 5;

    float acc[8] = {};
    const float* abase = attn + ((size_t)nh * 1024 + i0) * 1024;
    const float* vbase = vb + (size_t)nh * 1024 * 32;

    for (int jc = 0; jc < 8; jc++) {
#pragma unroll
        for (int c = 0; c < 8; c++) {
            int fi = t + 256 * c;
            int r = fi >> 5, c4 = fi & 31;
            ((float4*)At[r])[c4] =
                ((const float4*)(abase + (size_t)r * 1024 + jc * 128))[c4];
        }
#pragma unroll
        for (int c = 0; c < 4; c++) {
            int fi = t + 256 * c;
            int r = fi >> 3, dg = fi & 7;
            ((float4*)Vs[r])[dg] =
                ((const float4*)(vbase + (size_t)(jc * 128 + r) * 32))[dg];
        }
        __syncthreads();
#pragma unroll
        for (int jj = 0; jj < 32; jj++) {
            float v0 = Vs[jj * 4 + 0][tx];
            float v1 = Vs[jj * 4 + 1][tx];
            float v2 = Vs[jj * 4 + 2][tx];
            float v3 = Vs[jj * 4 + 3][tx];
#pragma unroll
            for (int ii = 0; ii < 8; ii++) {
                float4 av = ((float4*)At[ty * 8 + ii])[jj];
                acc[ii] += av.x * v0 + av.y * v1 + av.z * v2 + av.w * v3;
            }
        }
        __syncthreads();
    }

#pragma unroll
    for (int ii = 0; ii < 8; ii++) {
        int i = i0 + ty * 8 + ii;
        ctx_b[((size_t)i * 4 + n) * 256 + h * 32 + tx] = f2bf(acc[ii]);
    }
}

// ---------------------------------------------------------------------------
// GLU
// ---------------------------------------------------------------------------
__global__ __launch_bounds__(256) void glu_kernel(
    const float* __restrict__ h1, float* __restrict__ g)
{
    int idx = blockIdx.x * 256 + threadIdx.x;
    int r = idx >> 9, c = idx & 511;
    float a = h1[(size_t)r * 1024 + c];
    float b = h1[(size_t)r * 1024 + 512 + c];
    g[idx] = a * sigmoidf_(b);
}

// ---------------------------------------------------------------------------
// depthwise conv (K=31, pad 15) + bias + DoubleSwish -> bf16
// ---------------------------------------------------------------------------
__global__ __launch_bounds__(256) void dwconv_kernel(
    const float* __restrict__ g, const float* __restrict__ w_dw,
    const float* __restrict__ b_dw, unsigned short* __restrict__ out)
{
    int idx = blockIdx.x * 256 + threadIdx.x;
    int c = idx & 511;
    int r = idx >> 9;
    int nn = r & 3, l = r >> 2;
    float acc = b_dw[c];
#pragma unroll
    for (int kk = 0; kk < 31; kk++) {
        int l2 = l + kk - 15;
        if (l2 >= 0 && l2 < 1024)
            acc += g[(((size_t)l2 * 4 + nn) << 9) + c] * w_dw[c * 31 + kk];
    }
    out[idx] = f2bf(acc * sigmoidf_(acc - 1.f));
}

// ---------------------------------------------------------------------------
// BasicNorm
// ---------------------------------------------------------------------------
__global__ __launch_bounds__(256) void norm_kernel(
    const float* __restrict__ x, const float* __restrict__ eps_p,
    float* __restrict__ out)
{
    int r = blockIdx.x, t = threadIdx.x;
    float a = x[(size_t)r * 512 + t];
    float b = x[(size_t)r * 512 + 256 + t];
    float ss = a * a + b * b;
#pragma unroll
    for (int d = 1; d < 64; d <<= 1) ss += __shfl_xor(ss, d);
    __shared__ float red[4];
    if ((t & 63) == 0) red[t >> 6] = ss;
    __syncthreads();
    float tot = red[0] + red[1] + red[2] + red[3];
    float scale = rsqrtf(tot * (1.f / 512.f) + __expf(eps_p[0]));
    out[(size_t)r * 512 + t] = a * scale;
    out[(size_t)r * 512 + 256 + t] = b * scale;
}

// ---------------------------------------------------------------------------
extern "C" void kernel_launch(void* const* d_in, const int* in_sizes, int n_in,
                              void* d_out, int out_size, void* d_ws, size_t ws_size,
                              hipStream_t stream)
{
    const float* src   = (const float*)d_in[0];
    const float* pos   = (const float*)d_in[1];
    const float* as_   = (const float*)d_in[2];
    const float* w_in  = (const float*)d_in[3];
    const float* b_in  = (const float*)d_in[4];
    const float* w_pos = (const float*)d_in[5];
    const float* pbu   = (const float*)d_in[6];
    const float* pbv   = (const float*)d_in[7];
    const float* prin  = (const float*)d_in[8];
    const float* prout = (const float*)d_in[9];
    const float* w_out = (const float*)d_in[10];
    const float* b_out = (const float*)d_in[11];
    const float* w_ff1m = (const float*)d_in[12];
    const float* b_ff1m = (const float*)d_in[13];
    const float* w_ff2m = (const float*)d_in[14];
    const float* b_ff2m = (const float*)d_in[15];
    const float* w_ff1 = (const float*)d_in[16];
    const float* b_ff1 = (const float*)d_in[17];
    const float* w_ff2 = (const float*)d_in[18];
    const float* b_ff2 = (const float*)d_in[19];
    const float* w_pw1 = (const float*)d_in[20];
    const float* b_pw1 = (const float*)d_in[21];
    const float* w_dw  = (const float*)d_in[22];
    const float* b_dw  = (const float*)d_in[23];
    const float* w_pw2 = (const float*)d_in[24];
    const float* b_pw2 = (const float*)d_in[25];
    const float* neps  = (const float*)d_in[26];

    float* out_x = (float*)d_out;                       // 4096*512
    float* out_s = (float*)d_out + 2097152;             // 4*1024*1024*8

    // ---- workspace layout (float units) ----
    float* ws = (float*)d_ws;
    float* xbuf = ws;                               // 2,097,152
    float* U    = xbuf + 2097152;                   // 6,291,456 (hb16 | hbuf+gbuf)
    float* sbbf = U + 6291456;                      // 1,048,576 (src bf16 | dbufb)
    float* xb16f= sbbf + 1048576;                   // 1,048,576
    float* qkvb = xb16f + 1048576;                  // 3,145,728 (later p2)
    float* qu   = qkvb + 3145728;                   // 1,048,576 (later ctxb)
    float* qv   = qu + 1048576;                     // 1,048,576
    float* kbuf = qv + 1048576;                     // 1,048,576
    float* vbuf = kbuf + 1048576;                   // 1,048,576
    float* pbuf = vbuf + 1048576;                   // 524,288
    float* wbf  = pbuf + 524288;                    // 524,288 (weight bf16 staging)
    float* tot  = wbf + 524288;                     // 33,554,432

    unsigned short* hb16  = (unsigned short*)U;           // 8,388,608 elems
    float*          hbuf  = U;                            // pw1 out (4096x1024)
    float*          gbuf  = U + 4194304;                  // GLU out (4096x512)
    unsigned short* sbb   = (unsigned short*)sbbf;        // src bf16 (2,097,152)
    unsigned short* dbufb = (unsigned short*)sbbf;        // dwconv out bf16
    unsigned short* xb16  = (unsigned short*)xb16f;       // x bf16 (2,097,152)
    unsigned short* ctxb  = (unsigned short*)qu;          // ctx bf16 (1,048,576)
    unsigned short* wb    = (unsigned short*)wbf;         // weight staging
    float*          p2    = qkvb;

    dim3 blk(256);
    const int M = 4096;

    // --- macaron FFN ---
    cast_bf16_kernel<<<2048, blk, 0, stream>>>((const float4*)src, (ushort4*)sbb);
    cast_bf16_kernel<<<1024, blk, 0, stream>>>((const float4*)w_ff1m, (ushort4*)wb);
    mfma_gemm<1,0,0,1><<<dim3(16, 32), blk, 0, stream>>>(
        sbb, wb, b_ff1m, nullptr, nullptr, hb16, M, 2048, 512);
    cast_bf16_kernel<<<1024, blk, 0, stream>>>((const float4*)w_ff2m, (ushort4*)wb);
    mfma_gemm<0,1,1,1><<<dim3(4, 32), blk, 0, stream>>>(
        hb16, wb, b_ff2m, src, xbuf, xb16, M, 512, 2048);

    // --- attention ---
    cast_bf16_kernel<<<384, blk, 0, stream>>>((const float4*)w_in, (ushort4*)wb);
    mfma_gemm<0,0,1,0><<<dim3(6, 32), blk, 0, stream>>>(
        xb16, wb, b_in, nullptr, qkvb, nullptr, M, 768, 512);
    gemm_kernel<<<dim3(4, 32), blk, 0, stream>>>(
        pos, w_pos, nullptr, pbuf, 2047, 256, 512);
    split_kernel<<<4096, blk, 0, stream>>>(qkvb, pbu, pbv, qu, qv, kbuf, vbuf);
    repack_p_kernel<<<2047, blk, 0, stream>>>(pbuf, p2);
    scores_kernel<<<dim3(16, 16, 32), blk, 0, stream>>>(qu, qv, kbuf, p2, tot);
    attn_finish_kernel<<<4096, blk, 0, stream>>>(tot, as_, prin, prout, out_s);
    ctx_kernel<<<dim3(16, 32), blk, 0, stream>>>(tot, vbuf, ctxb);
    cast_bf16_kernel<<<128, blk, 0, stream>>>((const float4*)w_out, (ushort4*)wb);
    mfma_gemm<0,1,1,1><<<dim3(4, 32), blk, 0, stream>>>(
        ctxb, wb, b_out, xbuf, xbuf, xb16, M, 512, 256);

    // --- conv module ---
    cast_bf16_kernel<<<512, blk, 0, stream>>>((const float4*)w_pw1, (ushort4*)wb);
    mfma_gemm<0,0,1,0><<<dim3(8, 32), blk, 0, stream>>>(
        xb16, wb, b_pw1, nullptr, hbuf, nullptr, M, 1024, 512);
    glu_kernel<<<8192, blk, 0, stream>>>(hbuf, gbuf);
    dwconv_kernel<<<8192, blk, 0, stream>>>(gbuf, w_dw, b_dw, dbufb);
    cast_bf16_kernel<<<256, blk, 0, stream>>>((const float4*)w_pw2, (ushort4*)wb);
    mfma_gemm<0,1,1,1><<<dim3(4, 32), blk, 0, stream>>>(
        dbufb, wb, b_pw2, xbuf, xbuf, xb16, M, 512, 512);

    // --- final FFN + BasicNorm ---
    cast_bf16_kernel<<<1024, blk, 0, stream>>>((const float4*)w_ff1, (ushort4*)wb);
    mfma_gemm<1,0,0,1><<<dim3(16, 32), blk, 0, stream>>>(
        xb16, wb, b_ff1, nullptr, nullptr, hb16, M, 2048, 512);
    cast_bf16_kernel<<<1024, blk, 0, stream>>>((const float4*)w_ff2, (ushort4*)wb);
    mfma_gemm<0,1,1,0><<<dim3(4, 32), blk, 0, stream>>>(
        hb16, wb, b_ff2, xbuf, xbuf, nullptr, M, 512, 2048);
    norm_kernel<<<4096, blk, 0, stream>>>(xbuf, neps, out_x);
}